// Round 10
// baseline (113.334 us; speedup 1.0000x reference)
//
#include <hip/hip_runtime.h>
#include <math.h>

#define BATCH 32
#define PTS   64
#define NPHI  8192

// ---------- fp64-core sincos (phi only — twice per thread) ----------
// Validated bit-faithful to numpy/JAX fp32 trig in rounds 3-9. q0/q1 feed
// every edge with pole-amplified sensitivity (sin phi near 1: ulp 6e-8).
__device__ __forceinline__ void sincosf_f64(float xf, float* s, float* c) {
    const double PIO2_HI = 1.57079632679489661923e+00;
    const double PIO2_LO = 6.12323399573676603587e-17;

    const float kf = __builtin_rintf(__fmul_rn(xf, 0.63661977236758138243f));
    const int   qi = (int)kf;
    const double kd = (double)kf;
    const double x  = (double)xf;

    double r = __builtin_fma(-kd, PIO2_HI, x);
    r = __builtin_fma(-kd, PIO2_LO, r);
    const double r2 = r * r;

    double ps = -2.50507602534068634195e-08;
    ps = __builtin_fma(ps, r2,  2.75573137070700676789e-06);
    ps = __builtin_fma(ps, r2, -1.98412698298579493134e-04);
    ps = __builtin_fma(ps, r2,  8.33333333332248946124e-03);
    ps = __builtin_fma(ps, r2, -1.66666666666666324348e-01);
    const double sinr = __builtin_fma(r * r2, ps, r);

    double pc =  2.08757232129817482790e-09;
    pc = __builtin_fma(pc, r2, -2.75573143513906633035e-07);
    pc = __builtin_fma(pc, r2,  2.48015872894767294178e-05);
    pc = __builtin_fma(pc, r2, -1.38888888888741095749e-03);
    pc = __builtin_fma(pc, r2,  4.16666666666666019037e-02);
    const double cosr = __builtin_fma(r2 * r2, pc, __builtin_fma(-0.5, r2, 1.0));

    const float sf = (float)sinr, cf = (float)cosr;
    const bool sw = (qi & 1);
    const float ss = sw ? cf : sf;
    const float cc = sw ? sf : cf;
    *s = (qi & 2)       ? -ss : ss;
    *c = ((qi + 1) & 2) ? -cc : cc;
}

// ---------- fp32 sincos for edge args (rounds 7-9 validated, absmax 0.199) --
__device__ __forceinline__ void sincosf_f32(float x, float* s, float* c) {
    const float C1 = 1.5707969665527344f;    // exact-product reduction const
    const float C2 = -6.3975783777e-7f;      // pi/2 - C1

    const float kf = __builtin_rintf(x * 0.63661977236758f);
    const int   qi = (int)kf;
    const float r1 = __builtin_fmaf(-kf, C1, x);   // exact
    const float r  = __builtin_fmaf(-kf, C2, r1);
    const float r2 = r * r;

    float ps = __builtin_fmaf(2.75573137e-06f, r2, -1.98412698e-04f);
    ps = __builtin_fmaf(ps, r2,  8.33333333e-03f);
    ps = __builtin_fmaf(ps, r2, -1.66666667e-01f);
    const float sr = __builtin_fmaf(r * r2, ps, r);

    float pc = __builtin_fmaf(-2.75573144e-07f, r2, 2.48015873e-05f);
    pc = __builtin_fmaf(pc, r2, -1.38888889e-03f);
    pc = __builtin_fmaf(pc, r2,  4.16666667e-02f);
    const float u  = __builtin_fmaf(r2 * r2, pc, -(0.5f * r2));
    const float cr = 1.0f + u;

    const bool sw = (qi & 1);
    const float ss = sw ? cr : sr;
    const float cc = sw ? sr : cr;
    *s = (qi & 2)       ? -ss : ss;
    *c = ((qi + 1) & 2) ? -cc : cc;
}

// One thread per (b, n-pair): handles n0 and n0+4096. dx/dy, vertex loads,
// addressing and loop overhead are n-independent -> shared across the two
// phi streams; the two independent chains provide in-thread ILP (total wave
// count halves to 2 waves/SIMD — the dual chains replace TLP with ILP).
//
// Per-n arithmetic is op-for-op identical to round 9 (validated absmax
// 0.1988525): dp exact 3-op fp32, ddq/ddqc exact (ddqc as sub == old
// nq1-add bitwise: fl(dx*nq1) = -fl(dx*q1) exactly, add is commutative),
// bit-exact 1e-4 mask, rcp + fp32 accumulation in the same order.
//
// blockIdx.z: output-base offset (0 for the real launch into d_out;
// probe launch uses grid.z=2 into d_ws for rocprof visibility).
__global__ __launch_bounds__(256, 2) void scatter_polygon_kernel(
    const float* __restrict__ points,   // [B, P, 2]
    const float* __restrict__ phi,      // [N]
    float* __restrict__ out)            // [B, 2, N] (+ z offset)
{
    __shared__ float2 spts[PTS];

    const int b = blockIdx.y;
    const int tid = threadIdx.x;
    const int n0 = blockIdx.x * 256 + tid;
    const int n1 = n0 + NPHI / 2;
    const size_t obase = (size_t)blockIdx.z * (2 * NPHI * BATCH);

    if (tid < PTS) {
        spts[tid] = reinterpret_cast<const float2*>(points)[b * PTS + tid];
    }
    __syncthreads();

    float q0a, q1a, sca, q0b, q1b, scb;
    {
        float s, c;
        sincosf_f64(phi[n0], &s, &c);
        q0a = c; q1a = __fsub_rn(s, 1.0f);
        sca = 1.0f / fabsf(__fadd_rn(__fmul_rn(q0a, q0a), __fmul_rn(q1a, q1a)));
        sincosf_f64(phi[n1], &s, &c);
        q0b = c; q1b = __fsub_rn(s, 1.0f);
        scb = 1.0f / fabsf(__fadd_rn(__fmul_rn(q0b, q0b), __fmul_rn(q1b, q1b)));
    }

    const float2 pv = spts[PTS - 1];            // prev vertex (roll by 1)
    float xp = pv.x, yp = pv.y;
    float s0a, c0a, s0b, c0b;
    sincosf_f32(__fadd_rn(__fmul_rn(xp, q0a), __fmul_rn(yp, q1a)), &s0a, &c0a);
    sincosf_f32(__fadd_rn(__fmul_rn(xp, q0b), __fmul_rn(yp, q1b)), &s0b, &c0b);

    float aRa = 0.0f, aIa = 0.0f, aRb = 0.0f, aIb = 0.0f;

    #pragma unroll 4
    for (int p = 0; p < PTS; ++p) {
        const float2 v = spts[p];
        const float dx = __fsub_rn(v.x, xp);    // n-independent: shared
        const float dy = __fsub_rn(v.y, yp);

        {   // stream a (n0)
            const float dp = __fadd_rn(__fmul_rn(v.x, q0a), __fmul_rn(v.y, q1a));
            float s1, c1;
            sincosf_f32(dp, &s1, &c1);
            const float ddq  = __fadd_rn(__fmul_rn(dx, q0a), __fmul_rn(dy, q1a));
            const float ddqc = __fsub_rn(__fmul_rn(dy, q0a), __fmul_rn(dx, q1a));
            const bool  m1  = (fabsf(ddq) >= 1e-4f);
            const float inv = __builtin_amdgcn_rcpf(ddq);
            const float dR = __fsub_rn(c0a, c1);
            const float dI = __fsub_rn(s0a, s1);
            const float gR = m1 ? (dR * inv) : s0a;
            const float gI = m1 ? (dI * inv) : (-c0a);
            aRa = __builtin_fmaf(ddqc, gR, aRa);
            aIa = __builtin_fmaf(ddqc, gI, aIa);
            s0a = s1; c0a = c1;
        }
        {   // stream b (n1) — independent chain, interleaves with a
            const float dp = __fadd_rn(__fmul_rn(v.x, q0b), __fmul_rn(v.y, q1b));
            float s1, c1;
            sincosf_f32(dp, &s1, &c1);
            const float ddq  = __fadd_rn(__fmul_rn(dx, q0b), __fmul_rn(dy, q1b));
            const float ddqc = __fsub_rn(__fmul_rn(dy, q0b), __fmul_rn(dx, q1b));
            const bool  m1  = (fabsf(ddq) >= 1e-4f);
            const float inv = __builtin_amdgcn_rcpf(ddq);
            const float dR = __fsub_rn(c0b, c1);
            const float dI = __fsub_rn(s0b, s1);
            const float gR = m1 ? (dR * inv) : s0b;
            const float gI = m1 ? (dI * inv) : (-c0b);
            aRb = __builtin_fmaf(ddqc, gR, aRb);
            aIb = __builtin_fmaf(ddqc, gI, aIb);
            s0b = s1; c0b = c1;
        }

        xp = v.x; yp = v.y;
    }

    float* o = out + obase + (size_t)b * 2 * NPHI;
    o[n0]        = sca * aRa;   // real
    o[NPHI + n0] = sca * aIa;   // imag
    o[n1]        = scb * aRb;
    o[NPHI + n1] = scb * aIb;
}

extern "C" void kernel_launch(void* const* d_in, const int* in_sizes, int n_in,
                              void* d_out, int out_size, void* d_ws, size_t ws_size,
                              hipStream_t stream) {
    const float* points = (const float*)d_in[0];  // [32, 64, 2] fp32
    const float* phi    = (const float*)d_in[1];  // [8192] fp32
    float* out          = (float*)d_out;          // [32, 2, 8192] fp32

    // Real launch: 16 x 32 blocks, z=1 -> writes d_out.
    dim3 grid(NPHI / 2 / 256, BATCH, 1);
    scatter_polygon_kernel<<<grid, 256, 0, stream>>>(points, phi, out);

    // DIAGNOSTIC PROBE (this round only): identical kernel at 2x grid into
    // d_ws (unvalidated scratch) so a >40us instance of this exact code
    // appears in the rocprof top-5 and yields real VALUBusy/Occupancy/VGPR.
    dim3 pgrid(NPHI / 2 / 256, BATCH, 2);
    scatter_polygon_kernel<<<pgrid, 256, 0, stream>>>(points, phi, (float*)d_ws);
}

// Round 11
// 79.995 us; speedup vs baseline: 1.4168x; 1.4168x over previous
//
#include <hip/hip_runtime.h>
#include <math.h>

#define BATCH 32
#define PTS   64
#define NPHI  8192

// ---------- fp64-core sincos (phi table only) ----------
// Validated bit-faithful to numpy/JAX fp32 trig in rounds 3-10. q0/q1 feed
// every edge with pole-amplified sensitivity (sin phi near 1: ulp 6e-8).
__device__ __forceinline__ void sincosf_f64(float xf, float* s, float* c) {
    const double PIO2_HI = 1.57079632679489661923e+00;
    const double PIO2_LO = 6.12323399573676603587e-17;

    const float kf = __builtin_rintf(__fmul_rn(xf, 0.63661977236758138243f));
    const int   qi = (int)kf;
    const double kd = (double)kf;
    const double x  = (double)xf;

    double r = __builtin_fma(-kd, PIO2_HI, x);
    r = __builtin_fma(-kd, PIO2_LO, r);
    const double r2 = r * r;

    double ps = -2.50507602534068634195e-08;
    ps = __builtin_fma(ps, r2,  2.75573137070700676789e-06);
    ps = __builtin_fma(ps, r2, -1.98412698298579493134e-04);
    ps = __builtin_fma(ps, r2,  8.33333333332248946124e-03);
    ps = __builtin_fma(ps, r2, -1.66666666666666324348e-01);
    const double sinr = __builtin_fma(r * r2, ps, r);

    double pc =  2.08757232129817482790e-09;
    pc = __builtin_fma(pc, r2, -2.75573143513906633035e-07);
    pc = __builtin_fma(pc, r2,  2.48015872894767294178e-05);
    pc = __builtin_fma(pc, r2, -1.38888888888741095749e-03);
    pc = __builtin_fma(pc, r2,  4.16666666666666019037e-02);
    const double cosr = __builtin_fma(r2 * r2, pc, __builtin_fma(-0.5, r2, 1.0));

    const float sf = (float)sinr, cf = (float)cosr;
    const bool sw = (qi & 1);
    const float ss = sw ? cf : sf;
    const float cc = sw ? sf : cf;
    *s = (qi & 2)       ? -ss : ss;
    *c = ((qi + 1) & 2) ? -cc : cc;
}

// Per-phi (q0, q1, scale) table — bit-preserving round-trip (validated R8).
__global__ __launch_bounds__(256) void phi_table_kernel(
    const float* __restrict__ phi, float4* __restrict__ qtab) {
    const int n = blockIdx.x * 256 + threadIdx.x;
    float s, c;
    sincosf_f64(phi[n], &s, &c);
    const float q0 = c;
    const float q1 = __fsub_rn(s, 1.0f);
    const float scale =
        1.0f / fabsf(__fadd_rn(__fmul_rn(q0, q0), __fmul_rn(q1, q1)));
    qtab[n] = make_float4(q0, q1, scale, 0.0f);
}

// Per-(b,p) edge table (x1, y1, dx, dy) — dx/dy are phi-independent; the
// __fsub_rn here is the identical op previously done per-thread (bitwise
// same result, computed once instead of 262144 times).
__global__ __launch_bounds__(256) void edge_table_kernel(
    const float* __restrict__ points, float4* __restrict__ etab) {
    const int i = blockIdx.x * 256 + threadIdx.x;   // i = b*PTS + p
    const int b = i >> 6;
    const int p = i & 63;
    const int pp = (p == 0) ? (PTS - 1) : (p - 1);
    const float x1 = points[(b * PTS + p) * 2];
    const float y1 = points[(b * PTS + p) * 2 + 1];
    const float x0 = points[(b * PTS + pp) * 2];
    const float y0 = points[(b * PTS + pp) * 2 + 1];
    etab[i] = make_float4(x1, y1, __fsub_rn(x1, x0), __fsub_rn(y1, y0));
}

// One thread per (b, n-pair): streams a=n0, b=n0+4096 (R10-validated packing).
// Edge data read through a block-uniform pointer with compile-time offsets
// in an unrolled loop -> scalarized to batched s_load on the scalar pipe:
// no LDS, no __syncthreads, no per-edge VALU address/load cost, no dx/dy
// subs, no fp64 in the hot loop. VALU ops use at most one SGPR operand.
//
// Per-n arithmetic is op-for-op identical to rounds 9/10 (validated absmax
// 0.1988525): dp exact 3-op fp32, ddq/ddqc exact, bit-exact 1e-4 mask,
// rcp + fp32 accumulation in the same order, scale applied at the end.
__global__ __launch_bounds__(256, 2) void scatter_polygon_kernel(
    const float4* __restrict__ etab,    // [B*P] (x, y, dx, dy)
    const float4* __restrict__ qtab,    // [N]   (q0, q1, scale, -)
    float* __restrict__ out)            // [B, 2, N]
{
    const int b = blockIdx.y;
    const int tid = threadIdx.x;
    const int n0 = blockIdx.x * 256 + tid;
    const int n1 = n0 + NPHI / 2;
    const float4* __restrict__ eb = etab + b * PTS;   // block-uniform base

    const float4 qva = qtab[n0];
    const float4 qvb = qtab[n1];
    const float q0a = qva.x, q1a = qva.y, sca = qva.z;
    const float q0b = qvb.x, q1b = qvb.y, scb = qvb.z;

    // previous vertex of edge 0 = vertex P-1 (uniform load)
    const float4 e63 = eb[PTS - 1];
    float s0a, c0a, s0b, c0b;
    {
        const float dpa = __fadd_rn(__fmul_rn(e63.x, q0a), __fmul_rn(e63.y, q1a));
        const float dpb = __fadd_rn(__fmul_rn(e63.x, q0b), __fmul_rn(e63.y, q1b));
        // fp32 sincos inlined below via helper
        // (declared after; forward use through lambda-free code order)
        // -- computed just after helper definition --
        // placeholder assignments replaced below
        s0a = dpa; s0b = dpb; c0a = 0.f; c0b = 0.f; // overwritten immediately
    }

    // ---------- fp32 sincos (rounds 7-10 validated, absmax 0.1988525) -----
    // high-amplification edges (scale large, phi near pi/2) have tiny args
    // -> kf=0, exact reduction, compensated cos (1+u): fp32 bits match
    // numpy's; kf!=0 only where scale <= ~40 (few-ulp dev ~1e-2 amplified).
    auto sincos32 = [](float x, float* s, float* c) {
        const float C1 = 1.5707969665527344f;
        const float C2 = -6.3975783777e-7f;
        const float kf = __builtin_rintf(x * 0.63661977236758f);
        const int   qi = (int)kf;
        const float r1 = __builtin_fmaf(-kf, C1, x);   // exact
        const float r  = __builtin_fmaf(-kf, C2, r1);
        const float r2 = r * r;
        float ps = __builtin_fmaf(2.75573137e-06f, r2, -1.98412698e-04f);
        ps = __builtin_fmaf(ps, r2,  8.33333333e-03f);
        ps = __builtin_fmaf(ps, r2, -1.66666667e-01f);
        const float sr = __builtin_fmaf(r * r2, ps, r);
        float pc = __builtin_fmaf(-2.75573144e-07f, r2, 2.48015873e-05f);
        pc = __builtin_fmaf(pc, r2, -1.38888889e-03f);
        pc = __builtin_fmaf(pc, r2,  4.16666667e-02f);
        const float u  = __builtin_fmaf(r2 * r2, pc, -(0.5f * r2));
        const float cr = 1.0f + u;
        const bool sw = (qi & 1);
        const float ss = sw ? cr : sr;
        const float cc = sw ? sr : cr;
        *s = (qi & 2)       ? -ss : ss;
        *c = ((qi + 1) & 2) ? -cc : cc;
    };

    sincos32(s0a, &s0a, &c0a);   // s0a held dpa
    sincos32(s0b, &s0b, &c0b);   // s0b held dpb

    float aRa = 0.0f, aIa = 0.0f, aRb = 0.0f, aIb = 0.0f;

    #pragma unroll 16
    for (int p = 0; p < PTS; ++p) {
        const float4 e = eb[p];   // uniform + constant offset -> s_load

        {   // stream a (n0)
            const float dp = __fadd_rn(__fmul_rn(e.x, q0a), __fmul_rn(e.y, q1a));
            float s1, c1;
            sincos32(dp, &s1, &c1);
            const float ddq  = __fadd_rn(__fmul_rn(e.z, q0a), __fmul_rn(e.w, q1a));
            const float ddqc = __fsub_rn(__fmul_rn(e.w, q0a), __fmul_rn(e.z, q1a));
            const bool  m1  = (fabsf(ddq) >= 1e-4f);
            const float inv = __builtin_amdgcn_rcpf(ddq);
            const float dR = __fsub_rn(c0a, c1);
            const float dI = __fsub_rn(s0a, s1);
            const float gR = m1 ? (dR * inv) : s0a;
            const float gI = m1 ? (dI * inv) : (-c0a);
            aRa = __builtin_fmaf(ddqc, gR, aRa);
            aIa = __builtin_fmaf(ddqc, gI, aIa);
            s0a = s1; c0a = c1;
        }
        {   // stream b (n1) — independent chain (ILP)
            const float dp = __fadd_rn(__fmul_rn(e.x, q0b), __fmul_rn(e.y, q1b));
            float s1, c1;
            sincos32(dp, &s1, &c1);
            const float ddq  = __fadd_rn(__fmul_rn(e.z, q0b), __fmul_rn(e.w, q1b));
            const float ddqc = __fsub_rn(__fmul_rn(e.w, q0b), __fmul_rn(e.z, q1b));
            const bool  m1  = (fabsf(ddq) >= 1e-4f);
            const float inv = __builtin_amdgcn_rcpf(ddq);
            const float dR = __fsub_rn(c0b, c1);
            const float dI = __fsub_rn(s0b, s1);
            const float gR = m1 ? (dR * inv) : s0b;
            const float gI = m1 ? (dI * inv) : (-c0b);
            aRb = __builtin_fmaf(ddqc, gR, aRb);
            aIb = __builtin_fmaf(ddqc, gI, aIb);
            s0b = s1; c0b = c1;
        }
    }

    float* o = out + (size_t)b * 2 * NPHI;
    o[n0]        = sca * aRa;   // real
    o[NPHI + n0] = sca * aIa;   // imag
    o[n1]        = scb * aRb;
    o[NPHI + n1] = scb * aIb;
}

extern "C" void kernel_launch(void* const* d_in, const int* in_sizes, int n_in,
                              void* d_out, int out_size, void* d_ws, size_t ws_size,
                              hipStream_t stream) {
    const float* points = (const float*)d_in[0];  // [32, 64, 2] fp32
    const float* phi    = (const float*)d_in[1];  // [8192] fp32
    float* out          = (float*)d_out;          // [32, 2, 8192] fp32

    float4* etab = (float4*)d_ws;                         // 2048 * 16 B
    float4* qtab = (float4*)((char*)d_ws + 32768);        // 8192 * 16 B

    edge_table_kernel<<<(BATCH * PTS) / 256, 256, 0, stream>>>(points, etab);
    phi_table_kernel<<<NPHI / 256, 256, 0, stream>>>(phi, qtab);

    dim3 grid(NPHI / 2 / 256, BATCH);   // 16 x 32 = 512 blocks
    scatter_polygon_kernel<<<grid, 256, 0, stream>>>(etab, qtab, out);
}

// Round 12
// 73.072 us; speedup vs baseline: 1.5510x; 1.0947x over previous
//
#include <hip/hip_runtime.h>
#include <math.h>

#define BATCH 32
#define PTS   64
#define NPHI  8192

// ---------- fp64-core sincos (phi only — ONCE per thread, lane-pair shared) --
// Validated bit-faithful to numpy/JAX fp32 trig in rounds 3-11. q0/q1 feed
// every edge with pole-amplified sensitivity (sin phi near 1: ulp 6e-8),
// so phi's trig must stay at fp64 accuracy.
__device__ __forceinline__ void sincosf_f64(float xf, float* s, float* c) {
    const double PIO2_HI = 1.57079632679489661923e+00;
    const double PIO2_LO = 6.12323399573676603587e-17;

    const float kf = __builtin_rintf(__fmul_rn(xf, 0.63661977236758138243f));
    const int   qi = (int)kf;
    const double kd = (double)kf;
    const double x  = (double)xf;

    double r = __builtin_fma(-kd, PIO2_HI, x);
    r = __builtin_fma(-kd, PIO2_LO, r);
    const double r2 = r * r;

    double ps = -2.50507602534068634195e-08;
    ps = __builtin_fma(ps, r2,  2.75573137070700676789e-06);
    ps = __builtin_fma(ps, r2, -1.98412698298579493134e-04);
    ps = __builtin_fma(ps, r2,  8.33333333332248946124e-03);
    ps = __builtin_fma(ps, r2, -1.66666666666666324348e-01);
    const double sinr = __builtin_fma(r * r2, ps, r);

    double pc =  2.08757232129817482790e-09;
    pc = __builtin_fma(pc, r2, -2.75573143513906633035e-07);
    pc = __builtin_fma(pc, r2,  2.48015872894767294178e-05);
    pc = __builtin_fma(pc, r2, -1.38888888888741095749e-03);
    pc = __builtin_fma(pc, r2,  4.16666666666666019037e-02);
    const double cosr = __builtin_fma(r2 * r2, pc, __builtin_fma(-0.5, r2, 1.0));

    const float sf = (float)sinr, cf = (float)cosr;
    const bool sw = (qi & 1);
    const float ss = sw ? cf : sf;
    const float cc = sw ? sf : cf;
    *s = (qi & 2)       ? -ss : ss;
    *c = ((qi + 1) & 2) ? -cc : cc;
}

// ---------- fp32 sincos for edge args (rounds 7-11 validated noise band) ----
// Same arithmetic as R7-R10 (coeffs, op order). Only the quadrant SIGN
// application is re-lowered: (qi&2)? -v : v  ==  v ^ ((qi<<30)&0x80000000)
// bit-exactly (float negation = sign-bit flip; identical qi&2 semantics).
// Error structure (R6/R7): high-amplification n (scale large, phi~pi/2)
// have tiny args -> kf=0, exact reduction, compensated cos (1+u) matches
// numpy's fp32 bits; kf!=0 only where scale <= ~40 (dev ~1e-2 amplified).
__device__ __forceinline__ void sincos32(float x, float* s, float* c) {
    const float C1 = 1.5707969665527344f;    // exact-product reduction const
    const float C2 = -6.3975783777e-7f;      // pi/2 - C1

    const float kf = __builtin_rintf(x * 0.63661977236758f);
    const int   qi = (int)kf;
    const float r1 = __builtin_fmaf(-kf, C1, x);   // exact
    const float r  = __builtin_fmaf(-kf, C2, r1);
    const float r2 = r * r;

    float ps = __builtin_fmaf(2.75573137e-06f, r2, -1.98412698e-04f);
    ps = __builtin_fmaf(ps, r2,  8.33333333e-03f);
    ps = __builtin_fmaf(ps, r2, -1.66666667e-01f);
    const float sr = __builtin_fmaf(r * r2, ps, r);

    float pc = __builtin_fmaf(-2.75573144e-07f, r2, 2.48015873e-05f);
    pc = __builtin_fmaf(pc, r2, -1.38888889e-03f);
    pc = __builtin_fmaf(pc, r2,  4.16666667e-02f);
    const float u  = __builtin_fmaf(r2 * r2, pc, -(0.5f * r2));
    const float cr = 1.0f + u;

    const bool sw = (qi & 1);
    const float ss = sw ? cr : sr;
    const float cc = sw ? sr : cr;
    const unsigned ssign = ((unsigned)qi << 30) & 0x80000000u;        // qi&2 -> sign
    const unsigned csign = ((unsigned)(qi + 1) << 30) & 0x80000000u;  // (qi+1)&2
    *s = __uint_as_float(__float_as_uint(ss) ^ ssign);
    *c = __uint_as_float(__float_as_uint(cc) ^ csign);
}

// R10 structure (validated 21.9us, absmax 0.1988525) + lane-pair edge split:
// 256 threads = 128 n-pairs x 2 edge-halves. Thread (nidx, h) handles
// phi-streams a=n0, b=n0+4096 over edges [32h, 32h+32). Grid = 1024 blocks
// -> 4 blocks/CU = 4 waves/SIMD (matches the R10 probe's measured-78%-busy
// occupancy; real R10 launch only had 2). fp64 phi-sincos computed once per
// thread (own stream) and exchanged across the lane pair via shfl_xor.
// Per-stream edge arithmetic is op-for-op identical to R10; only the final
// combine order changes ([0,32)-sum + [32,64)-sum).
__global__ __launch_bounds__(256, 4) void scatter_polygon_kernel(
    const float* __restrict__ points,   // [B, P, 2]
    const float* __restrict__ phi,      // [N]
    float* __restrict__ out)            // [B, 2, N]
{
    __shared__ float2 spts[PTS];

    const int b = blockIdx.y;
    const int tid = threadIdx.x;
    const int h = tid & 1;                    // edge half
    const int nidx = tid >> 1;                // 0..127
    const int n0 = blockIdx.x * 128 + nidx;
    const int n1 = n0 + NPHI / 2;
    const int my_n = h ? n1 : n0;

    if (tid < PTS) {
        spts[tid] = reinterpret_cast<const float2*>(points)[b * PTS + tid];
    }
    __syncthreads();

    // one fp64 sincos per thread; lane-pair exchange covers both streams
    float q0m, q1m, scm;
    {
        float s, c;
        sincosf_f64(phi[my_n], &s, &c);
        q0m = c;
        q1m = __fsub_rn(s, 1.0f);
        scm = 1.0f / fabsf(__fadd_rn(__fmul_rn(q0m, q0m), __fmul_rn(q1m, q1m)));
    }
    const float q0o = __shfl_xor(q0m, 1);
    const float q1o = __shfl_xor(q1m, 1);
    const float sco = __shfl_xor(scm, 1);
    const float q0a = h ? q0o : q0m, q1a = h ? q1o : q1m, sca = h ? sco : scm;
    const float q0b = h ? q0m : q0o, q1b = h ? q1m : q1o, scb = h ? scm : sco;

    // previous vertex of the half's first edge: h=0 -> vertex 63, h=1 -> 31
    const int pbase = h * (PTS / 2);
    const float2 pv = spts[(pbase + PTS - 1) & (PTS - 1)];
    float xp = pv.x, yp = pv.y;
    float s0a, c0a, s0b, c0b;
    sincos32(__fadd_rn(__fmul_rn(xp, q0a), __fmul_rn(yp, q1a)), &s0a, &c0a);
    sincos32(__fadd_rn(__fmul_rn(xp, q0b), __fmul_rn(yp, q1b)), &s0b, &c0b);

    float aRa = 0.0f, aIa = 0.0f, aRb = 0.0f, aIb = 0.0f;

    #pragma unroll 8
    for (int i = 0; i < PTS / 2; ++i) {
        const float2 v = spts[pbase + i];
        const float dx = __fsub_rn(v.x, xp);    // n-independent: shared
        const float dy = __fsub_rn(v.y, yp);

        {   // stream a (n0) — op-for-op R10 arithmetic
            const float dp = __fadd_rn(__fmul_rn(v.x, q0a), __fmul_rn(v.y, q1a));
            float s1, c1;
            sincos32(dp, &s1, &c1);
            const float ddq  = __fadd_rn(__fmul_rn(dx, q0a), __fmul_rn(dy, q1a));
            const float ddqc = __fsub_rn(__fmul_rn(dy, q0a), __fmul_rn(dx, q1a));
            const bool  m1  = (fabsf(ddq) >= 1e-4f);
            const float inv = __builtin_amdgcn_rcpf(ddq);
            const float dR = __fsub_rn(c0a, c1);
            const float dI = __fsub_rn(s0a, s1);
            const float gR = m1 ? (dR * inv) : s0a;
            const float gI = m1 ? (dI * inv) : (-c0a);
            aRa = __builtin_fmaf(ddqc, gR, aRa);
            aIa = __builtin_fmaf(ddqc, gI, aIa);
            s0a = s1; c0a = c1;
        }
        {   // stream b (n1) — independent chain (ILP)
            const float dp = __fadd_rn(__fmul_rn(v.x, q0b), __fmul_rn(v.y, q1b));
            float s1, c1;
            sincos32(dp, &s1, &c1);
            const float ddq  = __fadd_rn(__fmul_rn(dx, q0b), __fmul_rn(dy, q1b));
            const float ddqc = __fsub_rn(__fmul_rn(dy, q0b), __fmul_rn(dx, q1b));
            const bool  m1  = (fabsf(ddq) >= 1e-4f);
            const float inv = __builtin_amdgcn_rcpf(ddq);
            const float dR = __fsub_rn(c0b, c1);
            const float dI = __fsub_rn(s0b, s1);
            const float gR = m1 ? (dR * inv) : s0b;
            const float gI = m1 ? (dI * inv) : (-c0b);
            aRb = __builtin_fmaf(ddqc, gR, aRb);
            aIb = __builtin_fmaf(ddqc, gI, aIb);
            s0b = s1; c0b = c1;
        }

        xp = v.x; yp = v.y;
    }

    // combine the two edge-halves (partner lane differs only in bit 0)
    aRa += __shfl_xor(aRa, 1);
    aIa += __shfl_xor(aIa, 1);
    aRb += __shfl_xor(aRb, 1);
    aIb += __shfl_xor(aIb, 1);

    float* o = out + (size_t)b * 2 * NPHI;
    if (h == 0) {
        o[n0]        = sca * aRa;   // real, stream a
        o[NPHI + n0] = sca * aIa;   // imag
    } else {
        o[n1]        = scb * aRb;   // real, stream b
        o[NPHI + n1] = scb * aIb;   // imag
    }
}

extern "C" void kernel_launch(void* const* d_in, const int* in_sizes, int n_in,
                              void* d_out, int out_size, void* d_ws, size_t ws_size,
                              hipStream_t stream) {
    const float* points = (const float*)d_in[0];  // [32, 64, 2] fp32
    const float* phi    = (const float*)d_in[1];  // [8192] fp32
    float* out          = (float*)d_out;          // [32, 2, 8192] fp32

    dim3 grid(NPHI / 2 / 128, BATCH);   // 32 x 32 = 1024 blocks, 4 blocks/CU
    scatter_polygon_kernel<<<grid, 256, 0, stream>>>(points, phi, out);
}

// Round 13
// 72.676 us; speedup vs baseline: 1.5594x; 1.0054x over previous
//
#include <hip/hip_runtime.h>
#include <math.h>

#define BATCH 32
#define PTS   64
#define NPHI  8192
#define NS    4          // phi-streams per thread

// ---------- fp64-core sincos (phi only — NS per thread at setup) ----------
// Validated bit-faithful to numpy/JAX fp32 trig in rounds 3-12. q0/q1 feed
// every edge with pole-amplified sensitivity (sin phi near 1: ulp 6e-8),
// so phi's trig must stay at fp64 accuracy.
__device__ __forceinline__ void sincosf_f64(float xf, float* s, float* c) {
    const double PIO2_HI = 1.57079632679489661923e+00;
    const double PIO2_LO = 6.12323399573676603587e-17;

    const float kf = __builtin_rintf(__fmul_rn(xf, 0.63661977236758138243f));
    const int   qi = (int)kf;
    const double kd = (double)kf;
    const double x  = (double)xf;

    double r = __builtin_fma(-kd, PIO2_HI, x);
    r = __builtin_fma(-kd, PIO2_LO, r);
    const double r2 = r * r;

    double ps = -2.50507602534068634195e-08;
    ps = __builtin_fma(ps, r2,  2.75573137070700676789e-06);
    ps = __builtin_fma(ps, r2, -1.98412698298579493134e-04);
    ps = __builtin_fma(ps, r2,  8.33333333332248946124e-03);
    ps = __builtin_fma(ps, r2, -1.66666666666666324348e-01);
    const double sinr = __builtin_fma(r * r2, ps, r);

    double pc =  2.08757232129817482790e-09;
    pc = __builtin_fma(pc, r2, -2.75573143513906633035e-07);
    pc = __builtin_fma(pc, r2,  2.48015872894767294178e-05);
    pc = __builtin_fma(pc, r2, -1.38888888888741095749e-03);
    pc = __builtin_fma(pc, r2,  4.16666666666666019037e-02);
    const double cosr = __builtin_fma(r2 * r2, pc, __builtin_fma(-0.5, r2, 1.0));

    const float sf = (float)sinr, cf = (float)cosr;
    const bool sw = (qi & 1);
    const float ss = sw ? cf : sf;
    const float cc = sw ? sf : cf;
    *s = (qi & 2)       ? -ss : ss;
    *c = ((qi + 1) & 2) ? -cc : cc;
}

// ---------- fp32 sincos for edge args (rounds 7-12 validated, 0.1988525) ----
// Same arithmetic as R7-R12 (coeffs, op order), sign-via-xor quadrant
// lowering validated bit-identical in R12. Error structure (R6/R7):
// high-amplification n (scale large, phi~pi/2) have tiny args -> kf=0,
// exact reduction, compensated cos (1+u) matches numpy's fp32 bits;
// kf!=0 only where scale <= ~40 (few-ulp dev ~1e-2 after amplification).
__device__ __forceinline__ void sincos32(float x, float* s, float* c) {
    const float C1 = 1.5707969665527344f;    // exact-product reduction const
    const float C2 = -6.3975783777e-7f;      // pi/2 - C1

    const float kf = __builtin_rintf(x * 0.63661977236758f);
    const int   qi = (int)kf;
    const float r1 = __builtin_fmaf(-kf, C1, x);   // exact
    const float r  = __builtin_fmaf(-kf, C2, r1);
    const float r2 = r * r;

    float ps = __builtin_fmaf(2.75573137e-06f, r2, -1.98412698e-04f);
    ps = __builtin_fmaf(ps, r2,  8.33333333e-03f);
    ps = __builtin_fmaf(ps, r2, -1.66666667e-01f);
    const float sr = __builtin_fmaf(r * r2, ps, r);

    float pc = __builtin_fmaf(-2.75573144e-07f, r2, 2.48015873e-05f);
    pc = __builtin_fmaf(pc, r2, -1.38888889e-03f);
    pc = __builtin_fmaf(pc, r2,  4.16666667e-02f);
    const float u  = __builtin_fmaf(r2 * r2, pc, -(0.5f * r2));
    const float cr = 1.0f + u;

    const bool sw = (qi & 1);
    const float ss = sw ? cr : sr;
    const float cc = sw ? sr : cr;
    const unsigned ssign = ((unsigned)qi << 30) & 0x80000000u;        // qi&2
    const unsigned csign = ((unsigned)(qi + 1) << 30) & 0x80000000u;  // (qi+1)&2
    *s = __uint_as_float(__float_as_uint(ss) ^ ssign);
    *c = __uint_as_float(__float_as_uint(cc) ^ csign);
}

// One thread per (b, n-quad): phi-streams n0 + j*2048, j=0..3, ALL 64 edges
// (R10's validated structure widened 2->4 streams). ds_read/dx/dy/loop
// control amortized over 4 evals; 4 independent sincos chains give ILP>=4,
// substituting for TLP at the forced 1 wave/SIMD (65536 threads total).
// Issue-bound regime (R10 probe: VALUBusy 78%, VGPR 36, 0 conflicts;
// R12's 4-waves/SIMD split REGRESSED -> more waves only duplicate setup).
//
// Per-stream arithmetic is op-for-op identical to R10/R12 (validated absmax
// 0.1988525): dp exact 3-op fp32, ddq/ddqc exact, bit-exact 1e-4 mask,
// rcp + fp32 accumulation in edge order 0..63, scale applied at the end.
__global__ __launch_bounds__(256, 1) void scatter_polygon_kernel(
    const float* __restrict__ points,   // [B, P, 2]
    const float* __restrict__ phi,      // [N]
    float* __restrict__ out)            // [B, 2, N]
{
    __shared__ float2 spts[PTS];

    const int b = blockIdx.y;
    const int tid = threadIdx.x;
    const int n0 = blockIdx.x * 256 + tid;      // grid.x = NPHI/NS/256 = 8

    if (tid < PTS) {
        spts[tid] = reinterpret_cast<const float2*>(points)[b * PTS + tid];
    }
    __syncthreads();

    float q0[NS], q1[NS], sc[NS], s0[NS], c0[NS], aR[NS], aI[NS];

    #pragma unroll
    for (int j = 0; j < NS; ++j) {
        float s, c;
        sincosf_f64(phi[n0 + j * (NPHI / NS)], &s, &c);
        q0[j] = c;
        q1[j] = __fsub_rn(s, 1.0f);
        sc[j] = 1.0f / fabsf(__fadd_rn(__fmul_rn(q0[j], q0[j]),
                                       __fmul_rn(q1[j], q1[j])));
        aR[j] = 0.0f;
        aI[j] = 0.0f;
    }

    // previous vertex = points[b, P-1] (roll by 1)
    const float2 pv = spts[PTS - 1];
    float xp = pv.x, yp = pv.y;
    #pragma unroll
    for (int j = 0; j < NS; ++j) {
        sincos32(__fadd_rn(__fmul_rn(xp, q0[j]), __fmul_rn(yp, q1[j])),
                 &s0[j], &c0[j]);
    }

    // hand-pipelined LDS read by one iteration (covers ds_read latency
    // at 1 wave/SIMD)
    float2 v = spts[0];

    #pragma unroll 4
    for (int p = 0; p < PTS; ++p) {
        const float2 vn = spts[(p + 1) & (PTS - 1)];   // prefetch next
        const float dx = __fsub_rn(v.x, xp);           // n-independent: shared
        const float dy = __fsub_rn(v.y, yp);

        #pragma unroll
        for (int j = 0; j < NS; ++j) {   // 4 independent streams (ILP)
            const float dp = __fadd_rn(__fmul_rn(v.x, q0[j]),
                                       __fmul_rn(v.y, q1[j]));
            float s1, c1;
            sincos32(dp, &s1, &c1);
            const float ddq  = __fadd_rn(__fmul_rn(dx, q0[j]),
                                         __fmul_rn(dy, q1[j]));
            const float ddqc = __fsub_rn(__fmul_rn(dy, q0[j]),
                                         __fmul_rn(dx, q1[j]));
            const bool  m1  = (fabsf(ddq) >= 1e-4f);
            const float inv = __builtin_amdgcn_rcpf(ddq);
            const float dR = __fsub_rn(c0[j], c1);
            const float dI = __fsub_rn(s0[j], s1);
            const float gR = m1 ? (dR * inv) : s0[j];
            const float gI = m1 ? (dI * inv) : (-c0[j]);
            aR[j] = __builtin_fmaf(ddqc, gR, aR[j]);
            aI[j] = __builtin_fmaf(ddqc, gI, aI[j]);
            s0[j] = s1;
            c0[j] = c1;
        }

        xp = v.x; yp = v.y;
        v = vn;
    }

    float* o = out + (size_t)b * 2 * NPHI;
    #pragma unroll
    for (int j = 0; j < NS; ++j) {
        o[n0 + j * (NPHI / NS)]        = sc[j] * aR[j];   // real
        o[NPHI + n0 + j * (NPHI / NS)] = sc[j] * aI[j];   // imag
    }
}

extern "C" void kernel_launch(void* const* d_in, const int* in_sizes, int n_in,
                              void* d_out, int out_size, void* d_ws, size_t ws_size,
                              hipStream_t stream) {
    const float* points = (const float*)d_in[0];  // [32, 64, 2] fp32
    const float* phi    = (const float*)d_in[1];  // [8192] fp32
    float* out          = (float*)d_out;          // [32, 2, 8192] fp32

    dim3 grid(NPHI / NS / 256, BATCH);   // 8 x 32 = 256 blocks, 1 block/CU
    scatter_polygon_kernel<<<grid, 256, 0, stream>>>(points, phi, out);
}